// Round 1
// baseline (476.385 us; speedup 1.0000x reference)
//
#include <hip/hip_runtime.h>

typedef unsigned short u16;
typedef __bf16 bf16x8 __attribute__((ext_vector_type(8)));
typedef float f32x4 __attribute__((ext_vector_type(4)));

#define SEQQ 4096
#define HID 2048
#define HD 128
#define NBLK 64
#define ATT_SCALE 0.08838834764831843f

__device__ __forceinline__ u16 f2bf(float f) {
    unsigned u = __float_as_uint(f);
    u += 0x7fffu + ((u >> 16) & 1u);
    return (u16)(u >> 16);
}

__device__ __forceinline__ void gload_lds16(const void* g, void* l) {
    __builtin_amdgcn_global_load_lds((const __attribute__((address_space(1))) void*)g,
                                     (__attribute__((address_space(3))) void*)l, 16, 0, 0);
}

// ---------------- fp32 -> bf16 conversion ----------------
__global__ __launch_bounds__(256) void cvt_bf16_k(const float* __restrict__ in,
                                                  u16* __restrict__ out, int n4) {
    int i = blockIdx.x * 256 + threadIdx.x;
    if (i < n4) {
        float4 v = ((const float4*)in)[i];
        ushort4 o;
        o.x = f2bf(v.x); o.y = f2bf(v.y); o.z = f2bf(v.z); o.w = f2bf(v.w);
        ((ushort4*)out)[i] = o;
    }
}

// ---------------- bf16 GEMM:  C[M,N] = A[M,K] @ B[N,K]^T ----------------
// MODE: 0 = f32 out, 1 = bf16 out, 2 = bf16 transposed out (C[n*M + m])
template <int MODE>
__global__ __launch_bounds__(256) void gemm_bt(const u16* __restrict__ A,
                                               const u16* __restrict__ B,
                                               void* __restrict__ C,
                                               int M, int N, int K) {
    __shared__ __align__(16) u16 As[128 * 32];
    __shared__ __align__(16) u16 Bs[128 * 32];
    const int t = threadIdx.x, w = t >> 6, l = t & 63;
    const int lg = l >> 4, ll = l & 15;
    const int mb = blockIdx.y, nb = blockIdx.x;
    const int wr = w >> 1, wc = w & 1;

    f32x4 acc[4][4] = {};

    // staging: wave w covers LDS chunks w (pass0) and w+4 (pass1); lane l -> base + l*16B
    const int sr = l >> 2;           // row within 16-row chunk
    const int sc = (l & 3) * 8;      // k element offset
    const u16* gA = A + (mb * 128 + w * 16 + sr) * K + sc;
    const u16* gB = B + (nb * 128 + w * 16 + sr) * K + sc;
    char* lA0 = (char*)As + w * 1024;
    char* lA1 = (char*)As + (w + 4) * 1024;
    char* lB0 = (char*)Bs + w * 1024;
    char* lB1 = (char*)Bs + (w + 4) * 1024;

    for (int kt = 0; kt < K; kt += 32) {
        __syncthreads();
        gload_lds16(gA + kt, lA0);
        gload_lds16(gA + 64 * K + kt, lA1);
        gload_lds16(gB + kt, lB0);
        gload_lds16(gB + 64 * K + kt, lB1);
        __syncthreads();

        bf16x8 af[4], bfr[4];
#pragma unroll
        for (int mi = 0; mi < 4; ++mi)
            af[mi] = *(const bf16x8*)&As[(wr * 64 + mi * 16 + ll) * 32 + lg * 8];
#pragma unroll
        for (int ni = 0; ni < 4; ++ni)
            bfr[ni] = *(const bf16x8*)&Bs[(wc * 64 + ni * 16 + ll) * 32 + lg * 8];
#pragma unroll
        for (int mi = 0; mi < 4; ++mi)
#pragma unroll
            for (int ni = 0; ni < 4; ++ni)
                acc[mi][ni] = __builtin_amdgcn_mfma_f32_16x16x32_bf16(af[mi], bfr[ni],
                                                                      acc[mi][ni], 0, 0, 0);
    }

    const int row0 = mb * 128 + wr * 64, col0 = nb * 128 + wc * 64;
#pragma unroll
    for (int mi = 0; mi < 4; ++mi)
#pragma unroll
        for (int ni = 0; ni < 4; ++ni) {
            f32x4 v = acc[mi][ni];
#pragma unroll
            for (int r = 0; r < 4; ++r) {
                int row = row0 + mi * 16 + lg * 4 + r;
                int col = col0 + ni * 16 + ll;
                if (MODE == 0)
                    ((float*)C)[row * N + col] = v[r];
                else if (MODE == 1)
                    ((u16*)C)[row * N + col] = f2bf(v[r]);
                else
                    ((u16*)C)[col * M + row] = f2bf(v[r]);
            }
        }
}

// ---------------- block-sparse attention ----------------
// grid (64 qblocks, 16 heads), 256 threads = 4 waves, wave w: q rows w*16..w*16+15
// Q,K: [SEQ][2048] bf16 ; Vt: [2048][SEQ] bf16 (d-major) ; Out: [SEQ][2048] bf16
__global__ __launch_bounds__(256) void sparse_attn(const u16* __restrict__ Q,
                                                   const u16* __restrict__ Kmat,
                                                   const u16* __restrict__ Vt,
                                                   const int* __restrict__ rnd,
                                                   u16* __restrict__ Out) {
    __shared__ __align__(16) char Plds[4 * 2048];  // per-wave 16x64 bf16 P tile, XOR-swizzled
    const int qb = blockIdx.x, h = blockIdx.y;
    const int t = threadIdx.x, w = t >> 6, l = t & 63;
    const int lg = l >> 4, ll = l & 15;

    // dedup'd block list: local {qb-1,qb,qb+1}, global {0,63}, random
    int blist[6];
    int nblk = 0;
    {
        int cands[6];
        cands[0] = qb - 1; cands[1] = qb; cands[2] = qb + 1;
        cands[3] = 0; cands[4] = NBLK - 1; cands[5] = rnd[qb];
        for (int c = 0; c < 6; ++c) {
            int b = cands[c];
            if (b < 0 || b >= NBLK) continue;
            bool dup = false;
            for (int j = 0; j < nblk; ++j) dup = dup || (blist[j] == b);
            if (!dup) blist[nblk++] = b;
        }
    }

    // Q fragments held in registers for the whole kernel
    bf16x8 qf[4];
    const int qrow = qb * 64 + w * 16 + ll;
#pragma unroll
    for (int kc = 0; kc < 4; ++kc)
        qf[kc] = *(const bf16x8*)&Q[qrow * HID + h * HD + kc * 32 + lg * 8];

    f32x4 o[8];
#pragma unroll
    for (int dt = 0; dt < 8; ++dt) o[dt] = (f32x4){0.f, 0.f, 0.f, 0.f};
    float mrun[4], lrun[4];
#pragma unroll
    for (int r = 0; r < 4; ++r) { mrun[r] = -1e30f; lrun[r] = 0.f; }

    char* Pw = Plds + w * 2048;

    for (int bi = 0; bi < nblk; ++bi) {
        const int kb = blist[bi];

        // S = Q K^T  (16 q-rows x 64 keys per wave)
        f32x4 s[4];
#pragma unroll
        for (int ct = 0; ct < 4; ++ct) s[ct] = (f32x4){0.f, 0.f, 0.f, 0.f};
#pragma unroll
        for (int ct = 0; ct < 4; ++ct) {
#pragma unroll
            for (int kc = 0; kc < 4; ++kc) {
                bf16x8 kf = *(const bf16x8*)&Kmat[(kb * 64 + ct * 16 + ll) * HID +
                                                  h * HD + kc * 32 + lg * 8];
                s[ct] = __builtin_amdgcn_mfma_f32_16x16x32_bf16(qf[kc], kf, s[ct], 0, 0, 0);
            }
        }

        // online softmax; row r lives at q=lg*4+r, its 64 cols spread over 16 lanes x 4 tiles
        float rmax[4];
#pragma unroll
        for (int r = 0; r < 4; ++r) {
            s[0][r] *= ATT_SCALE; s[1][r] *= ATT_SCALE;
            s[2][r] *= ATT_SCALE; s[3][r] *= ATT_SCALE;
            rmax[r] = fmaxf(fmaxf(s[0][r], s[1][r]), fmaxf(s[2][r], s[3][r]));
        }
#pragma unroll
        for (int mk = 1; mk <= 8; mk <<= 1)
#pragma unroll
            for (int r = 0; r < 4; ++r)
                rmax[r] = fmaxf(rmax[r], __shfl_xor(rmax[r], mk));

        float scl[4], psum[4];
#pragma unroll
        for (int r = 0; r < 4; ++r) {
            float mn = fmaxf(mrun[r], rmax[r]);
            scl[r] = __expf(mrun[r] - mn);
            mrun[r] = mn;
            psum[r] = 0.f;
        }

        // P = exp(S - m), staged to per-wave LDS (chunk-aligned XOR swizzle)
#pragma unroll
        for (int ct = 0; ct < 4; ++ct)
#pragma unroll
            for (int r = 0; r < 4; ++r) {
                float e = __expf(s[ct][r] - mrun[r]);
                psum[r] += e;
                const int q = lg * 4 + r;
                const int kv = ct * 16 + ll;
                *(u16*)(Pw + q * 128 + ((kv * 2) ^ ((q & 7) << 4))) = f2bf(e);
            }
#pragma unroll
        for (int mk = 1; mk <= 8; mk <<= 1)
#pragma unroll
            for (int r = 0; r < 4; ++r)
                psum[r] += __shfl_xor(psum[r], mk);
#pragma unroll
        for (int r = 0; r < 4; ++r)
            lrun[r] = lrun[r] * scl[r] + psum[r];
#pragma unroll
        for (int dt = 0; dt < 8; ++dt)
#pragma unroll
            for (int r = 0; r < 4; ++r)
                o[dt][r] *= scl[r];

        // O += P @ V   (A = P from swizzled LDS, B = V^T rows, contiguous 16B)
#pragma unroll
        for (int kc2 = 0; kc2 < 2; ++kc2) {
            bf16x8 pf = *(const bf16x8*)(Pw + ll * 128 +
                                         ((kc2 * 64 + lg * 16) ^ ((ll & 7) << 4)));
#pragma unroll
            for (int dt = 0; dt < 8; ++dt) {
                bf16x8 vf = *(const bf16x8*)&Vt[(h * HD + dt * 16 + ll) * SEQQ +
                                                kb * 64 + kc2 * 32 + lg * 8];
                o[dt] = __builtin_amdgcn_mfma_f32_16x16x32_bf16(pf, vf, o[dt], 0, 0, 0);
            }
        }
    }

    float rl[4];
#pragma unroll
    for (int r = 0; r < 4; ++r) rl[r] = 1.f / lrun[r];
#pragma unroll
    for (int dt = 0; dt < 8; ++dt)
#pragma unroll
        for (int r = 0; r < 4; ++r) {
            int row = qb * 64 + w * 16 + lg * 4 + r;
            int col = h * HD + dt * 16 + ll;
            Out[row * HID + col] = f2bf(o[dt][r] * rl[r]);
        }
}

// ---------------- launcher ----------------
extern "C" void kernel_launch(void* const* d_in, const int* in_sizes, int n_in,
                              void* d_out, int out_size, void* d_ws, size_t ws_size,
                              hipStream_t stream) {
    const float* hs = (const float*)d_in[0];
    const int* rnd = (const int*)d_in[1];
    const float* Wq = (const float*)d_in[2];
    const float* Wk = (const float*)d_in[3];
    const float* Wv = (const float*)d_in[4];
    const float* Wo = (const float*)d_in[5];
    float* out = (float*)d_out;

    char* ws = (char*)d_ws;
    u16* hs_b = (u16*)(ws);                  // 16 MB  (4096x2048 bf16)
    u16* Wq_b = (u16*)(ws + 16777216);       // 8 MB
    u16* Wk_b = (u16*)(ws + 25165824);       // 8 MB
    u16* Wv_b = (u16*)(ws + 33554432);       // 8 MB
    u16* Wo_b = (u16*)(ws + 41943040);       // 8 MB
    u16* Qb   = (u16*)(ws + 50331648);       // 16 MB
    u16* Kb   = (u16*)(ws + 67108864);       // 16 MB
    u16* Vtb  = (u16*)(ws + 83886080);       // 16 MB  (transposed: [2048][4096])
    u16* Ab   = (u16*)(ws + 100663296);      // 16 MB  (attention out)

    cvt_bf16_k<<<dim3(8192), 256, 0, stream>>>(hs, hs_b, 8388608 / 4);
    cvt_bf16_k<<<dim3(4096), 256, 0, stream>>>(Wq, Wq_b, 4194304 / 4);
    cvt_bf16_k<<<dim3(4096), 256, 0, stream>>>(Wk, Wk_b, 4194304 / 4);
    cvt_bf16_k<<<dim3(4096), 256, 0, stream>>>(Wv, Wv_b, 4194304 / 4);
    cvt_bf16_k<<<dim3(4096), 256, 0, stream>>>(Wo, Wo_b, 4194304 / 4);

    dim3 gg(2048 / 128, 4096 / 128);  // (16, 32)
    gemm_bt<1><<<gg, 256, 0, stream>>>(hs_b, Wq_b, Qb, 4096, 2048, 2048);
    gemm_bt<1><<<gg, 256, 0, stream>>>(hs_b, Wk_b, Kb, 4096, 2048, 2048);
    gemm_bt<2><<<gg, 256, 0, stream>>>(hs_b, Wv_b, Vtb, 4096, 2048, 2048);

    sparse_attn<<<dim3(64, 16), 256, 0, stream>>>(Qb, Kb, Vtb, rnd, Ab);

    gemm_bt<0><<<gg, 256, 0, stream>>>(Ab, Wo_b, out, 4096, 2048, 2048);
}

// Round 2
// 417.530 us; speedup vs baseline: 1.1410x; 1.1410x over previous
//
#include <hip/hip_runtime.h>

typedef unsigned short u16;
typedef __bf16 bf16x8 __attribute__((ext_vector_type(8)));
typedef float f32x4 __attribute__((ext_vector_type(4)));

#define SEQQ 4096
#define HID 2048
#define HD 128
#define NBLK 64
#define ATT_SCALE 0.08838834764831843f

__device__ __forceinline__ u16 f2bf(float f) {
    unsigned u = __float_as_uint(f);
    u += 0x7fffu + ((u >> 16) & 1u);
    return (u16)(u >> 16);
}

__device__ __forceinline__ void gload_lds16(const void* g, void* l) {
    __builtin_amdgcn_global_load_lds((const __attribute__((address_space(1))) void*)g,
                                     (__attribute__((address_space(3))) void*)l, 16, 0, 0);
}

// ---------------- fp32 -> bf16 conversion ----------------
__global__ __launch_bounds__(256) void cvt_bf16_k(const float* __restrict__ in,
                                                  u16* __restrict__ out, int n4) {
    int i = blockIdx.x * 256 + threadIdx.x;
    if (i < n4) {
        float4 v = ((const float4*)in)[i];
        ushort4 o;
        o.x = f2bf(v.x); o.y = f2bf(v.y); o.z = f2bf(v.z); o.w = f2bf(v.w);
        ((ushort4*)out)[i] = o;
    }
}

// all four weights in one launch: y=0..2 -> qkv concat buffer, y=3 -> wo buffer
__global__ __launch_bounds__(256) void cvt4_k(const float* __restrict__ w0,
                                              const float* __restrict__ w1,
                                              const float* __restrict__ w2,
                                              const float* __restrict__ w3,
                                              u16* __restrict__ qkv,
                                              u16* __restrict__ wo) {
    const int y = blockIdx.y;
    const float* src = (y == 0) ? w0 : (y == 1) ? w1 : (y == 2) ? w2 : w3;
    u16* dst = (y < 3) ? (qkv + (size_t)y * 4194304) : wo;
    int i = blockIdx.x * 256 + threadIdx.x;  // 4096*256 = 1048576 float4 quads
    float4 v = ((const float4*)src)[i];
    ushort4 o;
    o.x = f2bf(v.x); o.y = f2bf(v.y); o.z = f2bf(v.z); o.w = f2bf(v.w);
    ((ushort4*)dst)[i] = o;
}

// ---------------- bf16 GEMM:  C[M,N] = A[M,K] @ B[N,K]^T ----------------
// MODE: 0 = f32 out, 3 = fused QKV split epilogue (C = Q base; K at +8M elems,
//        Vt (transposed [2048][4096]) at +16M elems)
template <int MODE>
__global__ __launch_bounds__(256) void gemm_bt(const u16* __restrict__ A,
                                               const u16* __restrict__ B,
                                               void* __restrict__ C,
                                               int M, int N, int K) {
    __shared__ __align__(16) u16 As[128 * 32];
    __shared__ __align__(16) u16 Bs[128 * 32];
    const int t = threadIdx.x, w = t >> 6, l = t & 63;
    const int lg = l >> 4, ll = l & 15;

    // XCD-aware swizzle (nwg % 8 == 0 guaranteed by caller), mb-fast decomposition
    // so each XCD covers a narrow band of nb (B-panels fit its private L2).
    const int gx = gridDim.x, gy = gridDim.y;
    const int nwg = gx * gy;
    int lid = blockIdx.y * gx + blockIdx.x;
    int swz = (lid & 7) * (nwg >> 3) + (lid >> 3);
    const int mb = swz % gy;
    const int nb = swz / gy;

    const int wr = w >> 1, wc = w & 1;

    f32x4 acc[4][4] = {};

    const int sr = l >> 2;           // row within 16-row chunk
    const int sc = (l & 3) * 8;      // k element offset
    const u16* gA = A + (size_t)(mb * 128 + w * 16 + sr) * K + sc;
    const u16* gB = B + (size_t)(nb * 128 + w * 16 + sr) * K + sc;
    char* lA0 = (char*)As + w * 1024;
    char* lA1 = (char*)As + (w + 4) * 1024;
    char* lB0 = (char*)Bs + w * 1024;
    char* lB1 = (char*)Bs + (w + 4) * 1024;

    for (int kt = 0; kt < K; kt += 32) {
        __syncthreads();
        gload_lds16(gA + kt, lA0);
        gload_lds16(gA + (size_t)64 * K + kt, lA1);
        gload_lds16(gB + kt, lB0);
        gload_lds16(gB + (size_t)64 * K + kt, lB1);
        __syncthreads();

        bf16x8 af[4], bfr[4];
#pragma unroll
        for (int mi = 0; mi < 4; ++mi)
            af[mi] = *(const bf16x8*)&As[(wr * 64 + mi * 16 + ll) * 32 + lg * 8];
#pragma unroll
        for (int ni = 0; ni < 4; ++ni)
            bfr[ni] = *(const bf16x8*)&Bs[(wc * 64 + ni * 16 + ll) * 32 + lg * 8];
#pragma unroll
        for (int mi = 0; mi < 4; ++mi)
#pragma unroll
            for (int ni = 0; ni < 4; ++ni)
                acc[mi][ni] = __builtin_amdgcn_mfma_f32_16x16x32_bf16(af[mi], bfr[ni],
                                                                      acc[mi][ni], 0, 0, 0);
    }

    const int row0 = mb * 128 + wr * 64, col0 = nb * 128 + wc * 64;
#pragma unroll
    for (int mi = 0; mi < 4; ++mi)
#pragma unroll
        for (int ni = 0; ni < 4; ++ni) {
            f32x4 v = acc[mi][ni];
#pragma unroll
            for (int r = 0; r < 4; ++r) {
                int row = row0 + mi * 16 + lg * 4 + r;
                int col = col0 + ni * 16 + ll;
                if (MODE == 0) {
                    ((float*)C)[(size_t)row * N + col] = v[r];
                } else {
                    u16* Cq = (u16*)C;
                    if (col < 2048)
                        Cq[(size_t)row * 2048 + col] = f2bf(v[r]);
                    else if (col < 4096)
                        Cq[8388608 + (size_t)row * 2048 + (col - 2048)] = f2bf(v[r]);
                    else
                        Cq[16777216 + (size_t)(col - 4096) * 4096 + row] = f2bf(v[r]);
                }
            }
        }
}

// ---------------- block-sparse attention (LDS-staged, double-buffered) ----------------
// grid (64 qblocks, 16 heads), 256 threads = 4 waves, wave w: q rows w*16..w*16+15
// Q,K: [SEQ][2048] bf16 ; Vt: [2048][SEQ] bf16 (d-major) ; Out: [SEQ][2048] bf16
__global__ __launch_bounds__(256) void sparse_attn(const u16* __restrict__ Q,
                                                   const u16* __restrict__ Kmat,
                                                   const u16* __restrict__ Vt,
                                                   const int* __restrict__ rnd,
                                                   u16* __restrict__ Out) {
    // K tile: 64 rows x 128 dims (256B rows, 16 chunks of 16B)
    // V tile: 128 dims x 64 seq (128B rows, 8 chunks of 16B)
    // chunk-XOR swizzle applied on the GLOBAL source (global_load_lds dest is linear)
    __shared__ __align__(16) u16 Ks[2][8192];
    __shared__ __align__(16) u16 Vs[2][8192];
    __shared__ __align__(16) char Plds[4 * 2048];  // per-wave 16x64 bf16 P, XOR-swizzled

    const int qb = blockIdx.x, h = blockIdx.y;
    const int t = threadIdx.x, w = t >> 6, l = t & 63;
    const int lg = l >> 4, ll = l & 15;

    // dedup'd block list: local {qb-1,qb,qb+1}, global {0,63}, random
    int blist[6];
    int nblk = 0;
    {
        int cands[6];
        cands[0] = qb - 1; cands[1] = qb; cands[2] = qb + 1;
        cands[3] = 0; cands[4] = NBLK - 1; cands[5] = rnd[qb];
        for (int c = 0; c < 6; ++c) {
            int b = cands[c];
            if (b < 0 || b >= NBLK) continue;
            bool dup = false;
            for (int j = 0; j < nblk; ++j) dup = dup || (blist[j] == b);
            if (!dup) blist[nblk++] = b;
        }
    }

    // stage one key-block's K+V tiles (8 gload_lds16 per thread)
    auto stage = [&](int buf, int kb) {
        const u16* kbase = Kmat + (size_t)(kb * 64) * HID + h * HD;
        const u16* vbase = Vt + (size_t)(h * HD) * SEQQ + kb * 64;
#pragma unroll
        for (int j = 0; j < 4; ++j) {
            int d = j * 256 + t;
            int kr = d >> 4, kc_ = (d & 15) ^ (kr & 7);
            gload_lds16(kbase + (size_t)kr * HID + kc_ * 8, &Ks[buf][d * 8]);
            int vr = d >> 3, vc = (d & 7) ^ (vr & 7);
            gload_lds16(vbase + (size_t)vr * SEQQ + vc * 8, &Vs[buf][d * 8]);
        }
    };

    // Q fragments held in registers for the whole kernel
    bf16x8 qf[4];
    const int qrow = qb * 64 + w * 16 + ll;
#pragma unroll
    for (int kc = 0; kc < 4; ++kc)
        qf[kc] = *(const bf16x8*)&Q[(size_t)qrow * HID + h * HD + kc * 32 + lg * 8];

    f32x4 o[8];
#pragma unroll
    for (int dt = 0; dt < 8; ++dt) o[dt] = (f32x4){0.f, 0.f, 0.f, 0.f};
    float mrun[4], lrun[4];
#pragma unroll
    for (int r = 0; r < 4; ++r) { mrun[r] = -1e30f; lrun[r] = 0.f; }

    char* Pw = Plds + w * 2048;

    stage(0, blist[0]);
    int cur = 0;

    for (int bi = 0; bi < nblk; ++bi) {
        if (bi + 1 < nblk) {
            stage(cur ^ 1, blist[bi + 1]);
            // wait for current buffer's 8 loads (8 newer in flight), then sync
            asm volatile("s_waitcnt vmcnt(8)\n\ts_barrier" ::: "memory");
        } else {
            asm volatile("s_waitcnt vmcnt(0)\n\ts_barrier" ::: "memory");
        }

        // S = Q K^T  (16 q-rows x 64 keys per wave), K from swizzled LDS
        f32x4 s[4];
#pragma unroll
        for (int ct = 0; ct < 4; ++ct) s[ct] = (f32x4){0.f, 0.f, 0.f, 0.f};
#pragma unroll
        for (int ct = 0; ct < 4; ++ct) {
            const int krow = ct * 16 + ll;
#pragma unroll
            for (int kc = 0; kc < 4; ++kc) {
                bf16x8 kf = *(const bf16x8*)&Ks[cur][krow * 128 +
                                                    (((kc * 4 + lg) ^ (krow & 7)) << 3)];
                s[ct] = __builtin_amdgcn_mfma_f32_16x16x32_bf16(qf[kc], kf, s[ct], 0, 0, 0);
            }
        }

        // online softmax; row r lives at q=lg*4+r, 64 cols spread over 16 lanes x 4 tiles
        float rmax[4];
#pragma unroll
        for (int r = 0; r < 4; ++r) {
            s[0][r] *= ATT_SCALE; s[1][r] *= ATT_SCALE;
            s[2][r] *= ATT_SCALE; s[3][r] *= ATT_SCALE;
            rmax[r] = fmaxf(fmaxf(s[0][r], s[1][r]), fmaxf(s[2][r], s[3][r]));
        }
#pragma unroll
        for (int mk = 1; mk <= 8; mk <<= 1)
#pragma unroll
            for (int r = 0; r < 4; ++r)
                rmax[r] = fmaxf(rmax[r], __shfl_xor(rmax[r], mk));

        float scl[4], psum[4];
#pragma unroll
        for (int r = 0; r < 4; ++r) {
            float mn = fmaxf(mrun[r], rmax[r]);
            scl[r] = __expf(mrun[r] - mn);
            mrun[r] = mn;
            psum[r] = 0.f;
        }

        // P = exp(S - m), staged to per-wave LDS (XOR swizzle)
#pragma unroll
        for (int ct = 0; ct < 4; ++ct)
#pragma unroll
            for (int r = 0; r < 4; ++r) {
                float e = __expf(s[ct][r] - mrun[r]);
                psum[r] += e;
                const int q = lg * 4 + r;
                const int kv = ct * 16 + ll;
                *(u16*)(Pw + q * 128 + ((kv * 2) ^ ((q & 7) << 4))) = f2bf(e);
            }
#pragma unroll
        for (int mk = 1; mk <= 8; mk <<= 1)
#pragma unroll
            for (int r = 0; r < 4; ++r)
                psum[r] += __shfl_xor(psum[r], mk);
#pragma unroll
        for (int r = 0; r < 4; ++r)
            lrun[r] = lrun[r] * scl[r] + psum[r];
#pragma unroll
        for (int dt = 0; dt < 8; ++dt)
#pragma unroll
            for (int r = 0; r < 4; ++r)
                o[dt][r] *= scl[r];

        // O += P @ V  (A = P from swizzled LDS, B = V^T rows from swizzled LDS)
#pragma unroll
        for (int kc2 = 0; kc2 < 2; ++kc2) {
            bf16x8 pf = *(const bf16x8*)(Pw + ll * 128 +
                                         ((kc2 * 64 + lg * 16) ^ ((ll & 7) << 4)));
#pragma unroll
            for (int dt = 0; dt < 8; ++dt) {
                const int vrow = dt * 16 + ll;
                bf16x8 vf = *(const bf16x8*)&Vs[cur][vrow * 64 +
                                                     (((kc2 * 4 + lg) ^ (vrow & 7)) << 3)];
                o[dt] = __builtin_amdgcn_mfma_f32_16x16x32_bf16(pf, vf, o[dt], 0, 0, 0);
            }
        }

        // all waves done reading `cur` before next iteration's stage overwrites it
        asm volatile("s_barrier" ::: "memory");
        cur ^= 1;
    }

    float rl[4];
#pragma unroll
    for (int r = 0; r < 4; ++r) rl[r] = 1.f / lrun[r];
#pragma unroll
    for (int dt = 0; dt < 8; ++dt)
#pragma unroll
        for (int r = 0; r < 4; ++r) {
            int row = qb * 64 + w * 16 + lg * 4 + r;
            int col = h * HD + dt * 16 + ll;
            Out[(size_t)row * HID + col] = f2bf(o[dt][r] * rl[r]);
        }
}

// ---------------- launcher ----------------
extern "C" void kernel_launch(void* const* d_in, const int* in_sizes, int n_in,
                              void* d_out, int out_size, void* d_ws, size_t ws_size,
                              hipStream_t stream) {
    const float* hs = (const float*)d_in[0];
    const int* rnd = (const int*)d_in[1];
    const float* Wq = (const float*)d_in[2];
    const float* Wk = (const float*)d_in[3];
    const float* Wv = (const float*)d_in[4];
    const float* Wo = (const float*)d_in[5];
    float* out = (float*)d_out;

    char* ws = (char*)d_ws;
    u16* hs_b   = (u16*)(ws);                  // 16 MB (4096x2048 bf16)
    u16* Wqkv_b = (u16*)(ws + 16777216);       // 24 MB ([Wq|Wk|Wv] rows, 6144x2048)
    u16* Wo_b   = (u16*)(ws + 41943040);       //  8 MB
    u16* Qb     = (u16*)(ws + 50331648);       // 16 MB
    u16* Kb     = (u16*)(ws + 67108864);       // 16 MB (= Qb + 8388608 elems)
    u16* Vtb    = (u16*)(ws + 83886080);       // 16 MB (transposed [2048][4096])
    u16* Ab     = (u16*)(ws + 100663296);      // 16 MB (attention out)

    cvt_bf16_k<<<dim3(8192), 256, 0, stream>>>(hs, hs_b, 8388608 / 4);
    cvt4_k<<<dim3(4096, 4), 256, 0, stream>>>(Wq, Wk, Wv, Wo, Wqkv_b, Wo_b);

    // fused QKV projection: C[4096,6144] = hs @ [Wq;Wk;Wv]^T, epilogue splits Q/K/Vt
    gemm_bt<3><<<dim3(48, 32), 256, 0, stream>>>(hs_b, Wqkv_b, Qb, 4096, 6144, 2048);

    sparse_attn<<<dim3(64, 16), 256, 0, stream>>>(Qb, Kb, Vtb, rnd, Ab);

    gemm_bt<0><<<dim3(16, 32), 256, 0, stream>>>(Ab, Wo_b, out, 4096, 2048, 2048);
}